// Round 3
// 1310.167 us; speedup vs baseline: 1.0336x; 1.0336x over previous
//
#include <hip/hip_runtime.h>
#include <math.h>

// Problem dims (fixed)
#define NOTES 78
#define IN_DIM 80
#define T_HID 64
#define N_HID 2
#define BATCH 64
#define TLEN 128
#define NSEQ (BATCH * NOTES)          // 4992 time-LSTM sequences
#define NBT  (BATCH * TLEN)           // 8192 note-LSTM sequences
#define SB   4                        // sequences per block in time-LSTM

__device__ __forceinline__ float sigf(float x) { return 1.0f / (1.0f + expf(-x)); }
__device__ __forceinline__ float rdl(float v, int k) {
    return __int_as_float(__builtin_amdgcn_readlane(__float_as_int(v), k));
}

// ---------------------------------------------------------------------------
// Fused time-LSTM + note-input projection.  R7 == R5 resubmit (2x infra fail).
//   R4 counters: VALUBusy 70% but 828us issued vs 449us useful -> the 160-reg
//   x weight tile (wA[20]+wB[20]) never fit in the 112 arch VGPRs; compiler
//   bounced weights through AGPR/scratch each step.
//   Fix: split K across 2x the waves. 512 thr = 8 waves:
//     waves 0-3: x-part, 2 gates/thread, k-half 40  -> 80 VGPR weights
//     waves 4-7: h-part, 2 gates/thread, k-half 32  -> 64 VGPR weights
//   Four LDS partial buffers; phase B (and gxn projection) on h-waves.
//   __launch_bounds__(512,4): VGPR cap 128 >= ~110 demand, 2 blocks/CU.
// ---------------------------------------------------------------------------
__global__ __launch_bounds__(512, 4)
void time_lstm_fused(const float* __restrict__ x,
                     const float* __restrict__ w_ih,
                     const float* __restrict__ w_hh,
                     const float* __restrict__ b_ih,
                     const float* __restrict__ b_hh,
                     const float* __restrict__ w_ih_n,
                     const float* __restrict__ b_ih_n,
                     const float* __restrict__ b_hh_n,
                     float* __restrict__ gxn) {
    __shared__ float hbuf[SB][T_HID];    // 1 KB
    __shared__ float Gx[2][SB][256];     // 8 KB  x-part partials (kh=0 incl bias)
    __shared__ float Gh[2][SB][256];     // 8 KB  h-part partials

    const int tid  = threadIdx.x;
    const int s0   = blockIdx.x * SB;
    const int wid  = tid >> 6;           // 0..3 = x-waves; 4..7 = h-waves
    const int lane = tid & 63;
    const bool isx = (wid < 4);
    const int lw   = isx ? wid : (wid - 4);
    const int kh   = lw >> 1;            // k-half index (0/1)
    const int gh   = lw & 1;             // gate-half index (0/1)
    const int g0   = (gh << 7) | (2 * lane);   // first of 2 owned gates

    // ---- weight registers: 2 gate rows x one k-half per thread ----
    float4 wA[10], wB[10];               // x: 10 f4 each; h: 8 f4 each
    float biasA = 0.0f, biasB = 0.0f;
    if (isx) {
        const float4* pA = (const float4*)(w_ih + (size_t)g0 * IN_DIM + 40 * kh);
        const float4* pB = (const float4*)(w_ih + (size_t)(g0 + 1) * IN_DIM + 40 * kh);
#pragma unroll
        for (int j = 0; j < 10; j++) { wA[j] = pA[j]; wB[j] = pB[j]; }
        if (kh == 0) {                   // bias counted exactly once
            biasA = b_ih[g0] + b_hh[g0];
            biasB = b_ih[g0 + 1] + b_hh[g0 + 1];
        }
    } else {
        const float4* pA = (const float4*)(w_hh + (size_t)g0 * T_HID + 32 * kh);
        const float4* pB = (const float4*)(w_hh + (size_t)(g0 + 1) * T_HID + 32 * kh);
#pragma unroll
        for (int j = 0; j < 8; j++) { wA[j] = pA[j]; wB[j] = pB[j]; }
    }

    // x row bases (uniform -> SGPR)
    const float* xr[SB];
#pragma unroll
    for (int s = 0; s < SB; s++) xr[s] = x + (size_t)(s0 + s) * TLEN * IN_DIM;

    // x load offset: lanes 0..39 hold the 40 k-values of this wave's half.
    // (clamp keeps t=127/kh=1 loads in-bounds; readlane only uses idx<=39)
    const int ol = 40 * kh + (lane < 39 ? lane : 39);

    float xa[SB], xna[SB];
    if (isx) {
#pragma unroll
        for (int s = 0; s < SB; s++) xa[s] = xr[s][ol];
    }

    // ---- h-wave identities: phase-B (seq=lw, unit=lane) + gxn projection ----
    float cst = 0.0f;
    const int hol = (kh << 5) | (lane & 31);   // LDS h operand, 2-way bcast (free)
    const int nj = (lane >> 3) & 7;
    const int nk = lane & 7;
    float wn[8];
    float nbias = 0.0f;
    float* gout = gxn;
    if (!isx) {
#pragma unroll
        for (int i = 0; i < 8; i++) wn[i] = w_ih_n[nj * 64 + nk * 8 + i];
        nbias = b_ih_n[nj] + b_hh_n[nj];
        const int sglb = s0 + lw;
        const int nb = sglb / NOTES, nn = sglb % NOTES;
        gout = gxn + ((size_t)nn * NBT + (size_t)nb * TLEN) * 8 + nj;
    }

    if (tid < SB * T_HID) hbuf[tid >> 6][tid & 63] = 0.0f;
    __syncthreads();

    for (int t = 0; t < TLEN; t++) {
        if (isx) {
            // prefetch x(t+1) into registers (latency hides under MAC loop)
            if (t + 1 < TLEN) {
#pragma unroll
                for (int s = 0; s < SB; s++) xna[s] = xr[s][(t + 1) * IN_DIM + ol];
            }
            // ---- phase A (x): 10 k4 x 4 seqs, 1 readlane feeds 2 fma ----
            float aA[SB], aB[SB];
#pragma unroll
            for (int s = 0; s < SB; s++) { aA[s] = biasA; aB[s] = biasB; }
#pragma unroll
            for (int k4 = 0; k4 < 10; k4++) {
                const float4 vA = wA[k4], vB = wB[k4];
#pragma unroll
                for (int s = 0; s < SB; s++) {
                    const float r0 = rdl(xa[s], 4 * k4 + 0);
                    const float r1 = rdl(xa[s], 4 * k4 + 1);
                    const float r2 = rdl(xa[s], 4 * k4 + 2);
                    const float r3 = rdl(xa[s], 4 * k4 + 3);
                    aA[s] = fmaf(vA.x, r0, aA[s]);  aB[s] = fmaf(vB.x, r0, aB[s]);
                    aA[s] = fmaf(vA.y, r1, aA[s]);  aB[s] = fmaf(vB.y, r1, aB[s]);
                    aA[s] = fmaf(vA.z, r2, aA[s]);  aB[s] = fmaf(vB.z, r2, aB[s]);
                    aA[s] = fmaf(vA.w, r3, aA[s]);  aB[s] = fmaf(vB.w, r3, aB[s]);
                }
            }
#pragma unroll
            for (int s = 0; s < SB; s++)
                *(float2*)&Gx[kh][s][g0] = make_float2(aA[s], aB[s]);
        } else {
            // ---- gxn for h_{t-1} ----
            if (t > 0) {
                float p = 0.0f;
#pragma unroll
                for (int i = 0; i < 8; i++) p = fmaf(wn[i], hbuf[lw][nk * 8 + i], p);
                p += __shfl_xor(p, 1);
                p += __shfl_xor(p, 2);
                p += __shfl_xor(p, 4);
                if (nk == 0) gout[(size_t)(t - 1) * 8] = p + nbias;
            }
            // ---- phase A (h): 8 k4 x 4 seqs ----
            float hv[SB];
#pragma unroll
            for (int s = 0; s < SB; s++) hv[s] = hbuf[s][hol];
            float aA[SB], aB[SB];
#pragma unroll
            for (int s = 0; s < SB; s++) { aA[s] = 0.0f; aB[s] = 0.0f; }
#pragma unroll
            for (int k4 = 0; k4 < 8; k4++) {
                const float4 vA = wA[k4], vB = wB[k4];
#pragma unroll
                for (int s = 0; s < SB; s++) {
                    const float r0 = rdl(hv[s], 4 * k4 + 0);
                    const float r1 = rdl(hv[s], 4 * k4 + 1);
                    const float r2 = rdl(hv[s], 4 * k4 + 2);
                    const float r3 = rdl(hv[s], 4 * k4 + 3);
                    aA[s] = fmaf(vA.x, r0, aA[s]);  aB[s] = fmaf(vB.x, r0, aB[s]);
                    aA[s] = fmaf(vA.y, r1, aA[s]);  aB[s] = fmaf(vB.y, r1, aB[s]);
                    aA[s] = fmaf(vA.z, r2, aA[s]);  aB[s] = fmaf(vB.z, r2, aB[s]);
                    aA[s] = fmaf(vA.w, r3, aA[s]);  aB[s] = fmaf(vB.w, r3, aB[s]);
                }
            }
#pragma unroll
            for (int s = 0; s < SB; s++)
                *(float2*)&Gh[kh][s][g0] = make_float2(aA[s], aB[s]);
        }
        __syncthreads();   // barrier 1: all 4 partial buffers complete

        if (!isx) {
            // ---- phase B: combine 4 partials, activate, update state ----
            const float i_p = Gx[0][lw][lane]       + Gx[1][lw][lane]
                            + Gh[0][lw][lane]       + Gh[1][lw][lane];
            const float f_p = Gx[0][lw][64 + lane]  + Gx[1][lw][64 + lane]
                            + Gh[0][lw][64 + lane]  + Gh[1][lw][64 + lane];
            const float g_p = Gx[0][lw][128 + lane] + Gx[1][lw][128 + lane]
                            + Gh[0][lw][128 + lane] + Gh[1][lw][128 + lane];
            const float o_p = Gx[0][lw][192 + lane] + Gx[1][lw][192 + lane]
                            + Gh[0][lw][192 + lane] + Gh[1][lw][192 + lane];
            cst = sigf(f_p) * cst + sigf(i_p) * tanhf(g_p);
            const float h = sigf(o_p) * tanhf(cst);
            hbuf[lw][lane] = h;
        } else if (t + 1 < TLEN) {
#pragma unroll
            for (int s = 0; s < SB; s++) xa[s] = xna[s];
        }
        __syncthreads();   // barrier 2: hbuf ready; partials free for reuse
    }

    // epilogue: gxn for h_127
    if (!isx) {
        float p = 0.0f;
#pragma unroll
        for (int i = 0; i < 8; i++) p = fmaf(wn[i], hbuf[lw][nk * 8 + i], p);
        p += __shfl_xor(p, 1);
        p += __shfl_xor(p, 2);
        p += __shfl_xor(p, 4);
        if (nk == 0) gout[(size_t)(TLEN - 1) * 8] = p + nbias;
    }
}

// ---------------------------------------------------------------------------
// Note-LSTM scan over 78 notes, fresh zero state per (b,t).
// One thread per bt. Output buffered 2 notes at a time with static
// indices (a runtime-indexed res[156] array was scratch-allocated).
// ---------------------------------------------------------------------------
__global__ __launch_bounds__(64)
void note_scan_kernel(const float* __restrict__ gxn,
                      const float* __restrict__ w_hh_n,
                      float* __restrict__ out) {
    const int bt = blockIdx.x * 64 + threadIdx.x;         // < 8192
    float wh[16];
#pragma unroll
    for (int i = 0; i < 16; i++) wh[i] = w_hh_n[i];       // [8][2] row-major
    float h0 = 0.f, h1 = 0.f, c0 = 0.f, c1 = 0.f;

    const float4* gp = (const float4*)gxn;                // f4 index = (n*NBT+bt)*2
    float4* op = (float4*)(out + (size_t)bt * (NOTES * N_HID));

    size_t idx = (size_t)bt * 2;
    float4 ga = gp[idx], gb = gp[idx + 1];
    for (int n0 = 0; n0 < NOTES; n0 += 2) {
        float r[4];
#pragma unroll
        for (int u = 0; u < 2; u++) {
            const int n = n0 + u;
            float4 na, nb2;
            if (n + 1 < NOTES) {
                const size_t nidx = ((size_t)(n + 1) * NBT + bt) * 2;
                na  = gp[nidx];
                nb2 = gp[nidx + 1];
            }
            const float i0 = ga.x + wh[0]  * h0 + wh[1]  * h1;
            const float i1 = ga.y + wh[2]  * h0 + wh[3]  * h1;
            const float f0 = ga.z + wh[4]  * h0 + wh[5]  * h1;
            const float f1 = ga.w + wh[6]  * h0 + wh[7]  * h1;
            const float g0 = gb.x + wh[8]  * h0 + wh[9]  * h1;
            const float g1 = gb.y + wh[10] * h0 + wh[11] * h1;
            const float o0 = gb.z + wh[12] * h0 + wh[13] * h1;
            const float o1 = gb.w + wh[14] * h0 + wh[15] * h1;
            c0 = sigf(f0) * c0 + sigf(i0) * tanhf(g0);
            c1 = sigf(f1) * c1 + sigf(i1) * tanhf(g1);
            h0 = sigf(o0) * tanhf(c0);
            h1 = sigf(o1) * tanhf(c1);
            r[2 * u + 0] = (h0 > 0.5f) ? 1.0f : 0.0f;
            r[2 * u + 1] = (h1 > 0.5f) ? 1.0f : 0.0f;
            ga = na; gb = nb2;
        }
        op[n0 >> 1] = make_float4(r[0], r[1], r[2], r[3]);
    }
}

// ---------------------------------------------------------------------------
extern "C" void kernel_launch(void* const* d_in, const int* in_sizes, int n_in,
                              void* d_out, int out_size, void* d_ws, size_t ws_size,
                              hipStream_t stream) {
    const float* x      = (const float*)d_in[0];  // (64,78,128,80)
    const float* w_ih_t = (const float*)d_in[1];  // (256,80)
    const float* w_hh_t = (const float*)d_in[2];  // (256,64)
    const float* b_ih_t = (const float*)d_in[3];  // (256)
    const float* b_hh_t = (const float*)d_in[4];  // (256)
    const float* w_ih_n = (const float*)d_in[5];  // (8,64)
    const float* w_hh_n = (const float*)d_in[6];  // (8,2)
    const float* b_ih_n = (const float*)d_in[7];  // (8)
    const float* b_hh_n = (const float*)d_in[8];  // (8)
    float* out = (float*)d_out;                   // (64,128,156)

    // workspace: gxn = [78][8192][8] fp32 = 20.4 MB
    float* gxn = (float*)d_ws;

    time_lstm_fused<<<NSEQ / SB, 512, 0, stream>>>(
        x, w_ih_t, w_hh_t, b_ih_t, b_hh_t, w_ih_n, b_ih_n, b_hh_n, gxn);
    note_scan_kernel<<<NBT / 64, 64, 0, stream>>>(gxn, w_hh_n, out);
}